// Round 6
// baseline (172.693 us; speedup 1.0000x reference)
//
#include <hip/hip_runtime.h>

#define N_ROWS 131072
#define DIM 64
#define KCODES 512
#define MARGIN 5e-5f
#define SCAN_RPB 512

typedef __attribute__((ext_vector_type(8))) short bf16x8;
typedef __attribute__((ext_vector_type(4))) float f32x4;

// ws layout (4-byte words):
// [0] loss_sum, [1..513) counts u32, [514..1026) bnp f32,
// [1028..33796) wfrag ushort[65536]: MFMA-fragment image,
//   [ch 8][part hi/lo 2][cti 4][s 2][lane 64][8 ushort]  (16KB per chunk)

__device__ __forceinline__ float sqr_nf(float x) {
    float s = x * x;
    asm("" : "+v"(s));   // numpy rounds the square before summing
    return s;
}

// numpy pairwise_sum for sum(p[d]^2, d=0..63)  [validated round 3, absmax 0]
__device__ __forceinline__ float np_sumsq64(const float* p) {
    float r[8];
    {
        float4 a = *reinterpret_cast<const float4*>(p);
        float4 b = *reinterpret_cast<const float4*>(p + 4);
        r[0] = sqr_nf(a.x); r[1] = sqr_nf(a.y); r[2] = sqr_nf(a.z); r[3] = sqr_nf(a.w);
        r[4] = sqr_nf(b.x); r[5] = sqr_nf(b.y); r[6] = sqr_nf(b.z); r[7] = sqr_nf(b.w);
    }
#pragma unroll
    for (int i = 8; i < 64; i += 8) {
        float4 a = *reinterpret_cast<const float4*>(p + i);
        float4 b = *reinterpret_cast<const float4*>(p + i + 4);
        r[0] += sqr_nf(a.x); r[1] += sqr_nf(a.y); r[2] += sqr_nf(a.z); r[3] += sqr_nf(a.w);
        r[4] += sqr_nf(b.x); r[5] += sqr_nf(b.y); r[6] += sqr_nf(b.z); r[7] += sqr_nf(b.w);
    }
    return ((r[0] + r[1]) + (r[2] + r[3])) + ((r[4] + r[5]) + (r[6] + r[7]));
}

__device__ __forceinline__ unsigned short f2bf(float f) {  // RNE, finite data
    unsigned u = __float_as_uint(f);
    u += 0x7fffu + ((u >> 16) & 1u);
    return (unsigned short)(u >> 16);
}
__device__ __forceinline__ float bf2f(unsigned short b) {
    return __uint_as_float(((unsigned)b) << 16);
}

__device__ __forceinline__ void cvtpair(float4 a, float4 b, bf16x8& hi, bf16x8& lo) {
    float v[8] = {a.x, a.y, a.z, a.w, b.x, b.y, b.z, b.w};
#pragma unroll
    for (int j = 0; j < 8; ++j) {
        unsigned short h = f2bf(v[j]);
        hi[j] = (short)h;
        lo[j] = (short)f2bf(v[j] - bf2f(h));
    }
}

// ---- precompute: W -> bf16 hi/lo fragment image (16KB chunks) + np norms ---
__global__ __launch_bounds__(256) void vq_wprep_k(
    const float* __restrict__ W, unsigned short* __restrict__ wfrag,
    float* __restrict__ bnp) {
    int code = blockIdx.x * 256 + threadIdx.x;   // 0..511
    float p[64];
#pragma unroll
    for (int i = 0; i < 16; ++i) {
        float4 v = reinterpret_cast<const float4*>(W)[code * 16 + i];
        p[i * 4 + 0] = v.x; p[i * 4 + 1] = v.y;
        p[i * 4 + 2] = v.z; p[i * 4 + 3] = v.w;
    }
    unsigned short hi[64], lo[64];
#pragma unroll
    for (int d = 0; d < 64; ++d) {
        hi[d] = f2bf(p[d]);
        lo[d] = f2bf(p[d] - bf2f(hi[d]));
    }
    {   // np pairwise codeword norm
        float r[8];
#pragma unroll
        for (int j = 0; j < 8; ++j) r[j] = sqr_nf(p[j]);
#pragma unroll
        for (int i = 1; i < 8; ++i)
#pragma unroll
            for (int j = 0; j < 8; ++j) r[j] += sqr_nf(p[i * 8 + j]);
        bnp[code] = ((r[0] + r[1]) + (r[2] + r[3])) + ((r[4] + r[5]) + (r[6] + r[7]));
    }
    const int ch = code >> 6, cti = (code >> 4) & 3, m = code & 15;
#pragma unroll
    for (int part = 0; part < 2; ++part) {
        const unsigned short* src = part ? lo : hi;
#pragma unroll
        for (int s = 0; s < 2; ++s)
#pragma unroll
            for (int kq = 0; kq < 4; ++kq) {
                int lane = kq * 16 + m;
                size_t off = ((((size_t)((ch * 2 + part) * 4 + cti)) * 2 + s) * 64 + lane) * 8;
                *reinterpret_cast<uint4*>(wfrag + off) =
                    *reinterpret_cast<const uint4*>(src + s * 32 + kq * 8);
            }
    }
}

// ---- main: MFMA scoring, 64 rows/block, grid 2048, high occupancy ----------
__global__ __launch_bounds__(256, 6) void vq_mfma_k(
    const float* __restrict__ X, const float* __restrict__ Wf,
    const unsigned short* __restrict__ wfrag, const float* __restrict__ bnp,
    float* __restrict__ out_q, float* __restrict__ out_idx,
    float* __restrict__ loss_sum, unsigned* __restrict__ counts) {
    __shared__ __align__(16) unsigned short Wlds[8192];  // 16KB chunk image
    __shared__ float bnp_s[KCODES];
    __shared__ int idx_s[64];
    __shared__ float lred[4];

    const int tid = threadIdx.x;
    const int lane = tid & 63, w = tid >> 6;
    const int m = lane & 15, kq = lane >> 4;
    const long rbase = (long)blockIdx.x * 64;

    for (int i = tid; i < KCODES; i += 256) bnp_s[i] = bnp[i];

    // A-fragments (one 16-row tile per wave): lane (m,kq) holds A[m][kq*8+j]
    bf16x8 ahi[2], alo[2];
    {
        long row = rbase + w * 16 + m;
        const float4* xp = reinterpret_cast<const float4*>(X + row * DIM);
        cvtpair(xp[kq * 2], xp[kq * 2 + 1], ahi[0], alo[0]);
        cvtpair(xp[8 + kq * 2], xp[8 + kq * 2 + 1], ahi[1], alo[1]);
    }

    float best[4], sec[4];
    int bidx[4];
#pragma unroll
    for (int j = 0; j < 4; ++j) { best[j] = 3e38f; sec[j] = 3e38f; bidx[j] = 0; }

    for (int ch = 0; ch < 8; ++ch) {
        __syncthreads();
        {   // linear 16KB copy: frag image -> LDS (conflict-free reads later)
            const uint4* g = reinterpret_cast<const uint4*>(wfrag + ch * 8192);
            uint4* l4 = reinterpret_cast<uint4*>(Wlds);
#pragma unroll
            for (int i = 0; i < 4; ++i) l4[i * 256 + tid] = g[i * 256 + tid];
        }
        __syncthreads();

        const bf16x8* fp = reinterpret_cast<const bf16x8*>(Wlds);
#pragma unroll
        for (int cti = 0; cti < 4; ++cti) {
            bf16x8 bhi0 = fp[(cti * 2 + 0) * 64 + lane];
            bf16x8 bhi1 = fp[(cti * 2 + 1) * 64 + lane];
            bf16x8 blo0 = fp[((4 + cti) * 2 + 0) * 64 + lane];
            bf16x8 blo1 = fp[((4 + cti) * 2 + 1) * 64 + lane];
            const int kk = ch * 64 + cti * 16 + m;
            const float wn = bnp_s[kk];
            f32x4 a0 = {0.f, 0.f, 0.f, 0.f}, a1 = {0.f, 0.f, 0.f, 0.f};
            a0 = __builtin_amdgcn_mfma_f32_16x16x32_bf16(ahi[0], bhi0, a0, 0, 0, 0);
            a1 = __builtin_amdgcn_mfma_f32_16x16x32_bf16(ahi[1], bhi1, a1, 0, 0, 0);
            a0 = __builtin_amdgcn_mfma_f32_16x16x32_bf16(alo[0], bhi0, a0, 0, 0, 0);
            a1 = __builtin_amdgcn_mfma_f32_16x16x32_bf16(alo[1], bhi1, a1, 0, 0, 0);
            a0 = __builtin_amdgcn_mfma_f32_16x16x32_bf16(ahi[0], blo0, a0, 0, 0, 0);
            a1 = __builtin_amdgcn_mfma_f32_16x16x32_bf16(ahi[1], blo1, a1, 0, 0, 0);
            f32x4 acc = a0 + a1;
#pragma unroll
            for (int j = 0; j < 4; ++j) {
                float s = fmaf(-2.0f, acc[j], wn);   // A-free score, argmin-equiv
                if (s < best[j]) { sec[j] = best[j]; best[j] = s; bidx[j] = kk; }
                else if (s < sec[j]) sec[j] = s;
            }
        }
    }

    // merge across the 16 m-lanes; exact ties -> smaller index
#pragma unroll
    for (int st = 1; st < 16; st <<= 1) {
#pragma unroll
        for (int j = 0; j < 4; ++j) {
            float ob = __shfl_xor(best[j], st);
            float os = __shfl_xor(sec[j], st);
            int oi = __shfl_xor(bidx[j], st);
            if (ob < best[j] || (ob == best[j] && oi < bidx[j])) {
                sec[j] = fminf(best[j], os);
                best[j] = ob; bidx[j] = oi;
            } else {
                sec[j] = fminf(sec[j], ob);
            }
        }
    }

    // C/D row = kq*4 + j (lane m==0 holds merged result)
    if (m == 0) {
#pragma unroll
        for (int j = 0; j < 4; ++j) {
            int r = w * 16 + kq * 4 + j;
            int id = (sec[j] - best[j] <= MARGIN) ? -1 : bidx[j];
            idx_s[r] = id;
            out_idx[rbase + r] = (float)id;   // -1.0 sentinel -> refine
        }
    }
    __syncthreads();

    // fused epilogue: quantized_st + loss + counts (skip flagged rows)
    float ls = 0.f;
#pragma unroll
    for (int i = 0; i < 4; ++i) {
        int f = i * 1024 + tid * 4;
        int r = f >> 6, d = f & 63;
        int k = idx_s[r];
        if (k >= 0) {
            float4 x = *reinterpret_cast<const float4*>(&X[(rbase + r) * DIM + d]);
            float4 q = *reinterpret_cast<const float4*>(&Wf[k * DIM + d]);
            float4 o;
            float t;
            t = q.x - x.x; o.x = x.x + t; ls = fmaf(t, t, ls);
            t = q.y - x.y; o.y = x.y + t; ls = fmaf(t, t, ls);
            t = q.z - x.z; o.z = x.z + t; ls = fmaf(t, t, ls);
            t = q.w - x.w; o.w = x.w + t; ls = fmaf(t, t, ls);
            *reinterpret_cast<float4*>(&out_q[(rbase + r) * DIM + d]) = o;
        }
    }
#pragma unroll
    for (int st = 1; st < 64; st <<= 1) ls += __shfl_xor(ls, st);
    if (lane == 0) lred[w] = ls;
    __syncthreads();
    if (tid == 0) atomicAdd(loss_sum, lred[0] + lred[1] + lred[2] + lred[3]);
    if (tid < 64) {
        int k = idx_s[tid];
        if (k >= 0) atomicAdd(&counts[k], 1u);
    }
}

// ---- refine: np-bit-exact resolve of flagged rows, wave-per-row ------------
__global__ __launch_bounds__(256) void vq_refine_k(
    const float* __restrict__ X, const float* __restrict__ W,
    const float* __restrict__ bnp,
    float* __restrict__ out_q, float* __restrict__ out_idx,
    float* __restrict__ loss_sum, unsigned* __restrict__ counts) {
    __shared__ unsigned qrows[SCAN_RPB];
    __shared__ unsigned qn;
    const int tid = threadIdx.x;
    const int lane = tid & 63, wv = tid >> 6;
    const long r0 = (long)blockIdx.x * SCAN_RPB;

    if (tid == 0) qn = 0;
    __syncthreads();
    for (int i = tid; i < SCAN_RPB; i += 256)
        if (out_idx[r0 + i] < 0.f) qrows[atomicAdd(&qn, 1u)] = (unsigned)(r0 + i);
    __syncthreads();
    const unsigned nq = qn;

    for (unsigned jq = wv; jq < nq; jq += 4) {
        const long row = (long)qrows[jq];
        const float xv = X[row * DIM + lane];   // lane d holds x[d]

        // A = np pairwise sumsq, bit-exact: r[j] = seq sum of x[j+8i]^2,
        // then ((r0+r1)+(r2+r3))+((r4+r5)+(r6+r7))  (ordered shfl tree)
        float sq = sqr_nf(xv);
        float r = sq;
#pragma unroll
        for (int i = 1; i < 8; ++i) r += __shfl(sq, (lane & 7) + 8 * i);
        float t01 = r + __shfl_xor(r, 1);
        float t03 = t01 + __shfl_xor(t01, 2);
        float Afull = t03 + __shfl_xor(t03, 4);
        const float A = __shfl(Afull, 0);

        // dots: lane handles codes k = lane*8 + c, sequential over d (np/BLAS)
        float acc[8];
#pragma unroll
        for (int c = 0; c < 8; ++c) acc[c] = 0.f;
        for (int d0 = 0; d0 < 16; ++d0) {
            float x0 = __shfl(xv, d0 * 4 + 0);
            float x1 = __shfl(xv, d0 * 4 + 1);
            float x2 = __shfl(xv, d0 * 4 + 2);
            float x3 = __shfl(xv, d0 * 4 + 3);
#pragma unroll
            for (int c = 0; c < 8; ++c) {
                float4 wq = *reinterpret_cast<const float4*>(
                    &W[(lane * 8 + c) * DIM + d0 * 4]);
                acc[c] = fmaf(x0, wq.x, acc[c]);
                acc[c] = fmaf(x1, wq.y, acc[c]);
                acc[c] = fmaf(x2, wq.z, acc[c]);
                acc[c] = fmaf(x3, wq.w, acc[c]);
            }
        }
        float bs = 3e38f;
        int bi = 0;
#pragma unroll
        for (int c = 0; c < 8; ++c) {
            int k = lane * 8 + c;
            float u = A + bnp[k];
            float s = u - 2.0f * acc[c];
            if (s < bs) { bs = s; bi = k; }   // ascending k, strict <
        }
#pragma unroll
        for (int st = 1; st < 64; st <<= 1) {
            float ob = __shfl_xor(bs, st);
            int oi = __shfl_xor(bi, st);
            if (ob < bs || (ob == bs && oi < bi)) { bs = ob; bi = oi; }
        }
        const int k = bi;
        if (lane == 0) { out_idx[row] = (float)k; atomicAdd(&counts[k], 1u); }
        {
            float q = W[k * DIM + lane];
            float diff = q - xv;
            out_q[row * DIM + lane] = xv + diff;
            float l = diff * diff;
#pragma unroll
            for (int st = 1; st < 64; st <<= 1) l += __shfl_xor(l, st);
            if (lane == 0) atomicAdd(loss_sum, l);
        }
    }
}

__global__ __launch_bounds__(512) void vq_finalize_k(
    const float* __restrict__ loss_sum, const unsigned* __restrict__ counts,
    float* __restrict__ out_loss, float* __restrict__ out_perp) {
    __shared__ float red[512];
    int t = threadIdx.x;
    float p = (float)counts[t] * (1.0f / (float)N_ROWS);
    red[t] = p * logf(p + 1e-10f);
    __syncthreads();
    for (int off = 256; off; off >>= 1) {
        if (t < off) red[t] += red[t + off];
        __syncthreads();
    }
    if (t == 0) {
        *out_perp = expf(-red[0]);
        float mloss = *loss_sum / (float)(N_ROWS * DIM);
        *out_loss = mloss + 0.25f * mloss;
    }
}

extern "C" void kernel_launch(void* const* d_in, const int* in_sizes, int n_in,
                              void* d_out, int out_size, void* d_ws, size_t ws_size,
                              hipStream_t stream) {
    const float* X = (const float*)d_in[0];
    const float* Wf = (const float*)d_in[1];

    float* out = (float*)d_out;
    float* out_loss = out;
    float* out_q = out + 1;
    float* out_perp = out + 1 + (long)N_ROWS * DIM;
    float* out_idx = out + 2 + (long)N_ROWS * DIM;

    unsigned* wsu = (unsigned*)d_ws;
    float* loss_sum = (float*)d_ws;
    unsigned* counts = wsu + 1;
    float* bnp = (float*)(wsu + 514);
    unsigned short* wfrag = (unsigned short*)(wsu + 1028);

    hipMemsetAsync(d_ws, 0, 2056, stream);
    vq_wprep_k<<<2, 256, 0, stream>>>(Wf, wfrag, bnp);
    vq_mfma_k<<<N_ROWS / 64, 256, 0, stream>>>(X, Wf, wfrag, bnp,
                                               out_q, out_idx, loss_sum, counts);
    vq_refine_k<<<N_ROWS / SCAN_RPB, 256, 0, stream>>>(X, Wf, bnp, out_q, out_idx,
                                                       loss_sum, counts);
    vq_finalize_k<<<1, 512, 0, stream>>>(loss_sum, counts, out_loss, out_perp);
}

// Round 7
// 125.725 us; speedup vs baseline: 1.3736x; 1.3736x over previous
//
#include <hip/hip_runtime.h>

#define N_ROWS 131072
#define DIM 64
#define KCODES 512
#define MARGIN 5e-5f

typedef __attribute__((ext_vector_type(8))) short bf16x8;
typedef __attribute__((ext_vector_type(4))) float f32x4;

// ws layout (4-byte words):
// [0] loss_sum, [1..513) counts u32, [514..1026) bnp f32,
// [1028..33796) wfrag ushort[65536]: MFMA B-fragment image,
//   frag index = cti*256 + q*64 + lane   (bf16x8 units; 16B per frag)
//   q: 0=hi slice0, 1=hi slice1, 2=lo slice0, 3=lo slice1

__device__ __forceinline__ float sqr_nf(float x) {
    float s = x * x;
    asm("" : "+v"(s));   // numpy rounds the square before summing
    return s;
}

__device__ __forceinline__ unsigned short f2bf(float f) {  // RNE, finite data
    unsigned u = __float_as_uint(f);
    u += 0x7fffu + ((u >> 16) & 1u);
    return (unsigned short)(u >> 16);
}
__device__ __forceinline__ float bf2f(unsigned short b) {
    return __uint_as_float(((unsigned)b) << 16);
}

__device__ __forceinline__ void cvtpair(float4 a, float4 b, bf16x8& hi, bf16x8& lo) {
    float v[8] = {a.x, a.y, a.z, a.w, b.x, b.y, b.z, b.w};
#pragma unroll
    for (int j = 0; j < 8; ++j) {
        unsigned short h = f2bf(v[j]);
        hi[j] = (short)h;
        lo[j] = (short)f2bf(v[j] - bf2f(h));
    }
}

// ---- precompute: W -> bf16 hi/lo B-fragment image + np-exact norms ---------
__global__ __launch_bounds__(256) void vq_wprep_k(
    const float* __restrict__ W, unsigned short* __restrict__ wfrag,
    float* __restrict__ bnp) {
    int code = blockIdx.x * 256 + threadIdx.x;   // 0..511
    float p[64];
#pragma unroll
    for (int i = 0; i < 16; ++i) {
        float4 v = reinterpret_cast<const float4*>(W)[code * 16 + i];
        p[i * 4 + 0] = v.x; p[i * 4 + 1] = v.y;
        p[i * 4 + 2] = v.z; p[i * 4 + 3] = v.w;
    }
    unsigned short hi[64], lo[64];
#pragma unroll
    for (int d = 0; d < 64; ++d) {
        hi[d] = f2bf(p[d]);
        lo[d] = f2bf(p[d] - bf2f(hi[d]));
    }
    {   // np pairwise codeword norm  [validated round 3, absmax 0]
        float r[8];
#pragma unroll
        for (int j = 0; j < 8; ++j) r[j] = sqr_nf(p[j]);
#pragma unroll
        for (int i = 1; i < 8; ++i)
#pragma unroll
            for (int j = 0; j < 8; ++j) r[j] += sqr_nf(p[i * 8 + j]);
        bnp[code] = ((r[0] + r[1]) + (r[2] + r[3])) + ((r[4] + r[5]) + (r[6] + r[7]));
    }
    const int cti = code >> 4, m = code & 15;
#pragma unroll
    for (int part = 0; part < 2; ++part) {
        const unsigned short* src = part ? lo : hi;
#pragma unroll
        for (int s = 0; s < 2; ++s) {
            int q = part * 2 + s;
#pragma unroll
            for (int kq = 0; kq < 4; ++kq) {
                int lane = kq * 16 + m;
                size_t off = ((size_t)(cti * 4 + q) * 64 + lane) * 8;
                *reinterpret_cast<uint4*>(wfrag + off) =
                    *reinterpret_cast<const uint4*>(src + s * 32 + kq * 8);
            }
        }
    }
}

// ---- main: barrier-free MFMA scoring + fused epilogue + inline np refine ---
__global__ __launch_bounds__(256, 4) void vq_mfma_k(
    const float* __restrict__ X, const float* __restrict__ Wf,
    const unsigned short* __restrict__ wfrag, const float* __restrict__ bnp,
    float* __restrict__ out_q, float* __restrict__ out_idx,
    float* __restrict__ loss_sum, unsigned* __restrict__ counts) {
    __shared__ float bnp_s[KCODES];
    __shared__ int idx_s[128];
    __shared__ float lred[4];

    const int tid = threadIdx.x;
    const int lane = tid & 63, w = tid >> 6;
    const int m = lane & 15, kq = lane >> 4;
    const long rbase = (long)blockIdx.x * 128;

    for (int i = tid; i < KCODES; i += 256) bnp_s[i] = bnp[i];

    // A-fragments: 2 row-tiles per wave; lane (m,kq) holds A[m][kq*8+j]
    bf16x8 ahi[2][2], alo[2][2];
#pragma unroll
    for (int rt = 0; rt < 2; ++rt) {
        long row = rbase + w * 32 + rt * 16 + m;
        const float4* xp = reinterpret_cast<const float4*>(X + row * DIM);
        cvtpair(xp[kq * 2], xp[kq * 2 + 1], ahi[rt][0], alo[rt][0]);
        cvtpair(xp[8 + kq * 2], xp[8 + kq * 2 + 1], ahi[rt][1], alo[rt][1]);
    }
    __syncthreads();   // bnp_s ready

    float best[2][4], sec[2][4];
    int bidx[2][4];
#pragma unroll
    for (int rt = 0; rt < 2; ++rt)
#pragma unroll
        for (int j = 0; j < 4; ++j) { best[rt][j] = 3e38f; sec[rt][j] = 3e38f; bidx[rt][j] = 0; }

    const bf16x8* fb = reinterpret_cast<const bf16x8*>(wfrag);
    // 1-deep register prefetch; no barriers anywhere in this loop
    bf16x8 nb0 = fb[lane], nb1 = fb[64 + lane], nb2 = fb[128 + lane], nb3 = fb[192 + lane];
    for (int cti = 0; cti < 32; ++cti) {
        bf16x8 b0 = nb0, b1 = nb1, b2 = nb2, b3 = nb3;
        if (cti < 31) {
            int nbase = (cti + 1) * 256;
            nb0 = fb[nbase + lane];       nb1 = fb[nbase + 64 + lane];
            nb2 = fb[nbase + 128 + lane]; nb3 = fb[nbase + 192 + lane];
        }
        const int kk = cti * 16 + m;
        const float wn = bnp_s[kk];
#pragma unroll
        for (int rt = 0; rt < 2; ++rt) {
            f32x4 a0 = {0.f, 0.f, 0.f, 0.f}, a1 = {0.f, 0.f, 0.f, 0.f};
            a0 = __builtin_amdgcn_mfma_f32_16x16x32_bf16(ahi[rt][0], b0, a0, 0, 0, 0);
            a1 = __builtin_amdgcn_mfma_f32_16x16x32_bf16(ahi[rt][1], b1, a1, 0, 0, 0);
            a0 = __builtin_amdgcn_mfma_f32_16x16x32_bf16(alo[rt][0], b0, a0, 0, 0, 0);
            a1 = __builtin_amdgcn_mfma_f32_16x16x32_bf16(alo[rt][1], b1, a1, 0, 0, 0);
            a0 = __builtin_amdgcn_mfma_f32_16x16x32_bf16(ahi[rt][0], b2, a0, 0, 0, 0);
            a1 = __builtin_amdgcn_mfma_f32_16x16x32_bf16(ahi[rt][1], b3, a1, 0, 0, 0);
            f32x4 acc = a0 + a1;
#pragma unroll
            for (int j = 0; j < 4; ++j) {
                float s = fmaf(-2.0f, acc[j], wn);   // A-free score, argmin-equiv
                if (s < best[rt][j]) { sec[rt][j] = best[rt][j]; best[rt][j] = s; bidx[rt][j] = kk; }
                else if (s < sec[rt][j]) sec[rt][j] = s;
            }
        }
    }

    // merge across the 16 m-lanes; exact ties -> smaller index
#pragma unroll
    for (int st = 1; st < 16; st <<= 1) {
#pragma unroll
        for (int rt = 0; rt < 2; ++rt)
#pragma unroll
            for (int j = 0; j < 4; ++j) {
                float ob = __shfl_xor(best[rt][j], st);
                float os = __shfl_xor(sec[rt][j], st);
                int oi = __shfl_xor(bidx[rt][j], st);
                if (ob < best[rt][j] || (ob == best[rt][j] && oi < bidx[rt][j])) {
                    sec[rt][j] = fminf(best[rt][j], os);
                    best[rt][j] = ob; bidx[rt][j] = oi;
                } else {
                    sec[rt][j] = fminf(sec[rt][j], ob);
                }
            }
    }

    if (m == 0) {   // C/D row = kq*4 + j
#pragma unroll
        for (int rt = 0; rt < 2; ++rt)
#pragma unroll
            for (int j = 0; j < 4; ++j) {
                int r = w * 32 + rt * 16 + kq * 4 + j;
                int id = (sec[rt][j] - best[rt][j] <= MARGIN) ? -1 : bidx[rt][j];
                idx_s[r] = id;
                out_idx[rbase + r] = (float)id;   // sentinel overwritten below
            }
    }
    __syncthreads();

    // fused epilogue: quantized_st + loss (skip flagged rows)
    float ls = 0.f;
#pragma unroll
    for (int i = 0; i < 8; ++i) {
        int f = i * 1024 + tid * 4;
        int r = f >> 6, d = f & 63;
        int k = idx_s[r];
        if (k >= 0) {
            float4 x = *reinterpret_cast<const float4*>(&X[(rbase + r) * DIM + d]);
            float4 q = *reinterpret_cast<const float4*>(&Wf[k * DIM + d]);
            float4 o;
            float t;
            t = q.x - x.x; o.x = x.x + t; ls = fmaf(t, t, ls);
            t = q.y - x.y; o.y = x.y + t; ls = fmaf(t, t, ls);
            t = q.z - x.z; o.z = x.z + t; ls = fmaf(t, t, ls);
            t = q.w - x.w; o.w = x.w + t; ls = fmaf(t, t, ls);
            *reinterpret_cast<float4*>(&out_q[(rbase + r) * DIM + d]) = o;
        }
    }

    // inline np-bit-exact resolve of this wave's flagged rows [round-6 routine]
    for (int r = 0; r < 32; ++r) {
        if (idx_s[w * 32 + r] >= 0) continue;      // wave-uniform branch
        const long row = rbase + w * 32 + r;
        const float xv = X[row * DIM + lane];      // lane d holds x[d]
        // A = np pairwise sumsq (ordered shfl tree, bit-exact)
        float sq = sqr_nf(xv);
        float rr = sq;
#pragma unroll
        for (int i = 1; i < 8; ++i) rr += __shfl(sq, (lane & 7) + 8 * i);
        float t01 = rr + __shfl_xor(rr, 1);
        float t03 = t01 + __shfl_xor(t01, 2);
        float Afull = t03 + __shfl_xor(t03, 4);
        const float A = __shfl(Afull, 0);
        // dots: lane handles codes k = lane*8 + c, sequential over d (np/BLAS)
        float acc[8];
#pragma unroll
        for (int c = 0; c < 8; ++c) acc[c] = 0.f;
        for (int d0 = 0; d0 < 16; ++d0) {
            float x0 = __shfl(xv, d0 * 4 + 0);
            float x1 = __shfl(xv, d0 * 4 + 1);
            float x2 = __shfl(xv, d0 * 4 + 2);
            float x3 = __shfl(xv, d0 * 4 + 3);
#pragma unroll
            for (int c = 0; c < 8; ++c) {
                float4 wq = *reinterpret_cast<const float4*>(
                    &Wf[(lane * 8 + c) * DIM + d0 * 4]);
                acc[c] = fmaf(x0, wq.x, acc[c]);
                acc[c] = fmaf(x1, wq.y, acc[c]);
                acc[c] = fmaf(x2, wq.z, acc[c]);
                acc[c] = fmaf(x3, wq.w, acc[c]);
            }
        }
        float bs = 3e38f;
        int bi = 0;
#pragma unroll
        for (int c = 0; c < 8; ++c) {
            int k = lane * 8 + c;
            float u = A + bnp_s[k];
            float s = u - 2.0f * acc[c];
            if (s < bs) { bs = s; bi = k; }   // ascending k, strict <
        }
#pragma unroll
        for (int st = 1; st < 64; st <<= 1) {
            float ob = __shfl_xor(bs, st);
            int oi = __shfl_xor(bi, st);
            if (ob < bs || (ob == bs && oi < bi)) { bs = ob; bi = oi; }
        }
        const int k = bi;
        if (lane == 0) { out_idx[row] = (float)k; atomicAdd(&counts[k], 1u); }
        float qv = Wf[k * DIM + lane];
        float diff = qv - xv;
        out_q[row * DIM + lane] = xv + diff;
        ls = fmaf(diff, diff, ls);   // folded into the wave loss reduce below
    }

#pragma unroll
    for (int st = 1; st < 64; st <<= 1) ls += __shfl_xor(ls, st);
    if (lane == 0) lred[w] = ls;
    __syncthreads();
    if (tid == 0) atomicAdd(loss_sum, lred[0] + lred[1] + lred[2] + lred[3]);
    if (tid < 128) {
        int k = idx_s[tid];
        if (k >= 0) atomicAdd(&counts[k], 1u);
    }
}

__global__ __launch_bounds__(512) void vq_finalize_k(
    const float* __restrict__ loss_sum, const unsigned* __restrict__ counts,
    float* __restrict__ out_loss, float* __restrict__ out_perp) {
    __shared__ float red[512];
    int t = threadIdx.x;
    float p = (float)counts[t] * (1.0f / (float)N_ROWS);
    red[t] = p * logf(p + 1e-10f);
    __syncthreads();
    for (int off = 256; off; off >>= 1) {
        if (t < off) red[t] += red[t + off];
        __syncthreads();
    }
    if (t == 0) {
        *out_perp = expf(-red[0]);
        float mloss = *loss_sum / (float)(N_ROWS * DIM);
        *out_loss = mloss + 0.25f * mloss;
    }
}

extern "C" void kernel_launch(void* const* d_in, const int* in_sizes, int n_in,
                              void* d_out, int out_size, void* d_ws, size_t ws_size,
                              hipStream_t stream) {
    const float* X = (const float*)d_in[0];
    const float* Wf = (const float*)d_in[1];

    float* out = (float*)d_out;
    float* out_loss = out;
    float* out_q = out + 1;
    float* out_perp = out + 1 + (long)N_ROWS * DIM;
    float* out_idx = out + 2 + (long)N_ROWS * DIM;

    unsigned* wsu = (unsigned*)d_ws;
    float* loss_sum = (float*)d_ws;
    unsigned* counts = wsu + 1;
    float* bnp = (float*)(wsu + 514);
    unsigned short* wfrag = (unsigned short*)(wsu + 1028);

    hipMemsetAsync(d_ws, 0, 2056, stream);
    vq_wprep_k<<<2, 256, 0, stream>>>(Wf, wfrag, bnp);
    vq_mfma_k<<<N_ROWS / 128, 256, 0, stream>>>(X, Wf, wfrag, bnp,
                                                out_q, out_idx, loss_sum, counts);
    vq_finalize_k<<<1, 512, 0, stream>>>(loss_sum, counts, out_loss, out_perp);
}